// Round 6
// baseline (193.446 us; speedup 1.0000x reference)
//
#include <hip/hip_runtime.h>

#define D_DIM 1024
#define B_HALF 4096
#define NROWS 8192
#define INV_TEMP 10.0f
#define NT 32     // 8192 / 256 tiles per side
#define NKT 32    // 1024 / 32 K-tiles

typedef __bf16 bf16x8 __attribute__((ext_vector_type(8)));
typedef float floatx4 __attribute__((ext_vector_type(4)));

#define MFMA16 __builtin_amdgcn_mfma_f32_16x16x32_bf16

__device__ __forceinline__ unsigned short f32_to_bf16(float f) {
    union { float f; unsigned u; } v; v.f = f;
    unsigned r = 0x7FFFu + ((v.u >> 16) & 1u);
    return (unsigned short)((v.u + r) >> 16);
}

// Kernel 1: L2-normalize rows of z1,z2 -> bf16 R [8192][1024]; zero S.
__global__ __launch_bounds__(256) void normalize_kernel(
    const float* __restrict__ z1, const float* __restrict__ z2,
    unsigned short* __restrict__ R, float* __restrict__ S)
{
    const int row = blockIdx.x;
    const int tid = threadIdx.x;
    const float* src = (row < B_HALF) ? (z1 + (size_t)row * D_DIM)
                                      : (z2 + (size_t)(row - B_HALF) * D_DIM);
    float4 v = ((const float4*)src)[tid];
    if (tid == 0) S[row] = 0.0f;          // free re-zero every launch
    float ss = v.x * v.x + v.y * v.y + v.z * v.z + v.w * v.w;
    #pragma unroll
    for (int off = 32; off > 0; off >>= 1) ss += __shfl_down(ss, off);
    __shared__ float wsum[4];
    if ((tid & 63) == 0) wsum[tid >> 6] = ss;
    __syncthreads();
    float tot = wsum[0] + wsum[1] + wsum[2] + wsum[3];
    float scale = 1.0f / fmaxf(sqrtf(tot), 1e-12f);
    ushort4 o;
    o.x = f32_to_bf16(v.x * scale);
    o.y = f32_to_bf16(v.y * scale);
    o.z = f32_to_bf16(v.z * scale);
    o.w = f32_to_bf16(v.w * scale);
    ((ushort4*)(R + (size_t)row * D_DIM))[tid] = o;
}

// Kernel 2: 256x256 upper-tri tiles, 8 waves (2Mx4N), BK=32, QUAD-buffered
// LDS (128 KiB), depth-2 prefetch: iter kt stages tile kt+2 (4 gload/wave),
// single counted vmcnt(4) + ONE raw barrier per K-tile (never drain-to-0 in
// steady state). XOR slot-swizzle (slot ^= row&3) via pre-swizzled global
// source keeps ds_read_b128 at the 8-cyc conflict-free floor. Epilogue
// accumulates row/col exp-sums into S[] via atomics (per-block LDS reduce
// first).
__global__ __launch_bounds__(512, 2) void gemm_lse_kernel(
    const unsigned short* __restrict__ R,
    float* __restrict__ S, float* __restrict__ pos)
{
    __shared__ unsigned short lds[4][2][256 * 32];   // [buf][A/B][row*32+e] 128 KiB

    // XCD-aware swizzle (bijective: 528 = 8*66), then decode (rt,ct), rt<=ct
    int t = blockIdx.x;
    t = (t & 7) * 66 + (t >> 3);
    int rt = 0;
    while (t >= NT - rt) { t -= NT - rt; ++rt; }
    const int ct = rt + t;
    const bool isDiag = (rt == ct);

    const int tid = threadIdx.x;
    const int wave = tid >> 6, lane = tid & 63;
    const int wm = wave >> 2, wn = wave & 3;         // 2 x 4 wave grid
    const int row0 = rt * 256, col0 = ct * 256;
    const int lm = lane & 15, lq = lane >> 4;

    const unsigned short* __restrict__ gA = R + (size_t)row0 * D_DIM;
    const unsigned short* __restrict__ gB = R + (size_t)col0 * D_DIM;

    // staging: one issue = 64 lanes x 16B = 16 rows x 4 slots (1 KB), linear
    // LDS dest. Global slot pre-swizzled: s_g = (l&3) ^ (row&3).
    const int sRow = lane >> 2;                      // 0..15
    const int sCol = (lane & 3) ^ (sRow & 3);        // swizzled global 16B slot
    // read-side swizzled k-slot (frag row & 3 == lm & 3 for all frags)
    const int skA = (lq ^ (lm & 3)) * 8;
    const int aBase = (wm * 128 + lm) * 32 + skA;    // A rows wm*128+mi*16+lm
    const int bBase = (wn * 64 + lm) * 32 + skA;     // B rows wn*64+ni*16+lm

    floatx4 acc[8][4] = {};                          // 128 accumulators

#define STAGE(dstbuf, kk) \
    { _Pragma("unroll") for (int i = 0; i < 2; ++i) { \
        __builtin_amdgcn_global_load_lds( \
          (const __attribute__((address_space(1))) unsigned int*)(gA + (size_t)(wave * 32 + i * 16 + sRow) * D_DIM + (kk) + sCol * 8), \
          (__attribute__((address_space(3))) unsigned int*)(&lds[dstbuf][0][(wave * 32 + i * 16) * 32]), \
          16, 0, 0); \
        __builtin_amdgcn_global_load_lds( \
          (const __attribute__((address_space(1))) unsigned int*)(gB + (size_t)(wave * 32 + i * 16 + sRow) * D_DIM + (kk) + sCol * 8), \
          (__attribute__((address_space(3))) unsigned int*)(&lds[dstbuf][1][(wave * 32 + i * 16) * 32]), \
          16, 0, 0); \
      } }

    // prologue: stage tiles 0 and 1 (4 ops each); wait T0 only.
    STAGE(0, 0)
    STAGE(1, 32)
    asm volatile("s_waitcnt vmcnt(4)" ::: "memory");
    __builtin_amdgcn_s_barrier();

    for (int kt = 0; kt < NKT; ++kt) {
        const unsigned short* As = &lds[kt & 3][0][0];
        const unsigned short* Bs = &lds[kt & 3][1][0];

        if (kt + 2 < NKT) STAGE((kt + 2) & 3, (kt + 2) * 32)

        bf16x8 af[8], bf[4];
        #pragma unroll
        for (int mi = 0; mi < 8; ++mi)
            af[mi] = *(const bf16x8*)(As + aBase + mi * 512);
        #pragma unroll
        for (int ni = 0; ni < 4; ++ni)
            bf[ni] = *(const bf16x8*)(Bs + bBase + ni * 512);

        __builtin_amdgcn_s_setprio(1);
        #pragma unroll
        for (int mi = 0; mi < 8; ++mi)
            #pragma unroll
            for (int ni = 0; ni < 4; ++ni)
                acc[mi][ni] = MFMA16(af[mi], bf[ni], acc[mi][ni], 0, 0, 0);
        __builtin_amdgcn_s_setprio(0);

        // counted drain: leave tile kt+2's 4 loads in flight; tile kt+1 lands.
        if (kt + 2 < NKT)      { asm volatile("s_waitcnt vmcnt(4)" ::: "memory"); }
        else if (kt + 1 < NKT) { asm volatile("s_waitcnt vmcnt(0)" ::: "memory"); }
        __builtin_amdgcn_s_barrier();
    }

    // Epilogue: staging LDS dead -> overlay sums; per-block reduce, then
    // one atomicAdd per row/col into S.
    float* rowsum = (float*)&lds[0][0][0];   // [4][256]
    float* colsum = rowsum + 4 * 256;        // [2][256]

    float ecol[4] = {0.0f, 0.0f, 0.0f, 0.0f};
    #pragma unroll
    for (int mi = 0; mi < 8; ++mi) {
        const int rloc = wm * 128 + mi * 16 + lq * 4;
        #pragma unroll
        for (int reg = 0; reg < 4; ++reg) {
            const int gr = row0 + rloc + reg;
            float esum = 0.0f;
            #pragma unroll
            for (int ni = 0; ni < 4; ++ni) {
                const int gc = col0 + wn * 64 + ni * 16 + lm;
                float s = acc[mi][ni][reg] * INV_TEMP;
                if (gc == gr + B_HALF) { pos[gr] = s; pos[gc] = s; }
                float e = (gc == gr) ? 0.0f : __expf(s);
                esum += e;
                ecol[ni] += e;
            }
            esum += __shfl_xor(esum, 1);
            esum += __shfl_xor(esum, 2);
            esum += __shfl_xor(esum, 4);
            esum += __shfl_xor(esum, 8);
            if (lm == 0) rowsum[wn * 256 + rloc + reg] = esum;
        }
    }
    #pragma unroll
    for (int ni = 0; ni < 4; ++ni) {
        ecol[ni] += __shfl_xor(ecol[ni], 16);
        ecol[ni] += __shfl_xor(ecol[ni], 32);
    }
    if (lq == 0 && !isDiag) {
        #pragma unroll
        for (int ni = 0; ni < 4; ++ni)
            colsum[wm * 256 + wn * 64 + ni * 16 + lm] = ecol[ni];
    }
    __syncthreads();
    if (tid < 256) {
        float rs = rowsum[0 * 256 + tid] + rowsum[1 * 256 + tid]
                 + rowsum[2 * 256 + tid] + rowsum[3 * 256 + tid];
        atomicAdd(&S[row0 + tid], rs);
        if (!isDiag) {
            float cs = colsum[0 * 256 + tid] + colsum[1 * 256 + tid];
            atomicAdd(&S[col0 + tid], cs);
        }
    }
}

// Kernel 3: single block; loss = mean(log1p(S * exp(-pos))), written directly.
__global__ __launch_bounds__(1024) void finalize_kernel(
    const float* __restrict__ S, const float* __restrict__ pos,
    float* __restrict__ out)
{
    const int tid = threadIdx.x;
    float local = 0.0f;
    #pragma unroll
    for (int i = 0; i < 8; ++i) {
        const int r = i * 1024 + tid;
        local += log1pf(S[r] * __expf(-pos[r]));
    }
    #pragma unroll
    for (int off = 32; off > 0; off >>= 1) local += __shfl_down(local, off);
    __shared__ float ws[16];
    if ((tid & 63) == 0) ws[tid >> 6] = local;
    __syncthreads();
    if (tid == 0) {
        float tot = 0.0f;
        #pragma unroll
        for (int i = 0; i < 16; ++i) tot += ws[i];
        out[0] = tot * (1.0f / 8192.0f);
    }
}

extern "C" void kernel_launch(void* const* d_in, const int* in_sizes, int n_in,
                              void* d_out, int out_size, void* d_ws, size_t ws_size,
                              hipStream_t stream)
{
    const float* z1 = (const float*)d_in[0];
    const float* z2 = (const float*)d_in[1];
    float* out = (float*)d_out;
    char* ws = (char*)d_ws;
    unsigned short* R = (unsigned short*)ws;                      // 16 MiB bf16 reps
    float* pos = (float*)(ws + (size_t)16 * 1024 * 1024);         // 32 KiB [8192]
    float* S   = (float*)(ws + (size_t)16 * 1024 * 1024 + 65536); // 32 KiB [8192]

    normalize_kernel<<<NROWS, 256, 0, stream>>>(z1, z2, R, S);
    gemm_lse_kernel<<<528, 512, 0, stream>>>(R, S, pos);          // 32*33/2 upper-tri
    finalize_kernel<<<1, 1024, 0, stream>>>(S, pos, out);
}